// Round 1
// baseline (601.522 us; speedup 1.0000x reference)
//
#include <hip/hip_runtime.h>
#include <math.h>

#define HH 512
#define WW 512
#define BC 48
#define IMN (BC * HH * WW)   // 12,582,912

// ---------------------------------------------------------------------------
// P1/P3: horizontal 32-tap box sum along a row (optionally of squared values).
// Window for output j: cols [j-15, j+16], zero-padded outside [0,512).
// ---------------------------------------------------------------------------
__global__ __launch_bounds__(256) void k_hbox(const float* __restrict__ src,
                                              float* __restrict__ dst,
                                              int square)
{
    __shared__ float s[WW + 32];            // cols -15 .. 528
    const int row = blockIdx.x;             // bc*512 + i
    const long base = (long)row * WW;
    const int tid = threadIdx.x;
    for (int k = tid; k < WW + 32; k += 256) {
        int col = k - 15;
        float v = 0.f;
        if (col >= 0 && col < WW) {
            v = src[base + col];
            if (square) v *= v;
        }
        s[k] = v;
    }
    __syncthreads();
    for (int j = tid; j < WW; j += 256) {
        float sum = 0.f;
#pragma unroll
        for (int d = 0; d < 32; d++) sum += s[j + d];
        dst[base + j] = sum;
    }
}

// ---------------------------------------------------------------------------
// P2/P4: vertical 32-tap box sum of box_src (rows [i-15, i+16], zero pad),
// then pointwise combine with pt_src.
//   mode 0: dst = pt_src - boxsum/1024          (local-mean centering)
//   mode 1: dst = pt_src / sqrt(max(boxsum,0))  (energy normalization)
// Tile: 64 cols x 128 output rows; rolling window down columns.
// ---------------------------------------------------------------------------
__global__ __launch_bounds__(256) void k_vbox(const float* __restrict__ box_src,
                                              const float* __restrict__ pt_src,
                                              float* __restrict__ dst,
                                              int mode)
{
    __shared__ float s[159 * 64];           // rows i0-15 .. i0+143
    const int j0 = blockIdx.x * 64;
    const int i0 = blockIdx.y * 128;
    const int bc = blockIdx.z;
    const int tid = threadIdx.x;
    const long plane = (long)bc * HH * WW;
    for (int k = tid; k < 159 * 64; k += 256) {
        int r = k >> 6, c = k & 63;
        int gi = i0 + r - 15;
        s[k] = (gi >= 0 && gi < HH) ? box_src[plane + (long)gi * WW + j0 + c] : 0.f;
    }
    __syncthreads();
    const int tc = tid & 63;
    const int lr0 = (tid >> 6) * 32;        // 4 groups x 32 rows each
    float run = 0.f;
#pragma unroll
    for (int d = 0; d < 32; d++) run += s[(lr0 + d) * 64 + tc];
    for (int rr = 0; rr < 32; rr++) {
        int lr = lr0 + rr;
        int gi = i0 + lr;
        long g = plane + (long)gi * WW + j0 + tc;
        if (mode == 0) {
            dst[g] = pt_src[g] - run * (1.0f / 1024.0f);
        } else {
            float e = sqrtf(fmaxf(run, 0.f));
            dst[g] = pt_src[g] / e;
        }
        if (rr < 31) run += s[(lr + 32) * 64 + tc] - s[lr * 64 + tc];
    }
}

// ---------------------------------------------------------------------------
// Template normalization: Tn = (t - mean) / ||t - mean||_2 per (b,c).
// ---------------------------------------------------------------------------
__global__ __launch_bounds__(256) void k_template(const float* __restrict__ t,
                                                  float* __restrict__ tn)
{
    __shared__ float red[256];
    const int bc = blockIdx.x, tid = threadIdx.x;
    const float* tp = t + bc * 1024;
    float v0 = tp[tid], v1 = tp[tid + 256], v2 = tp[tid + 512], v3 = tp[tid + 768];
    red[tid] = v0 + v1 + v2 + v3;
    __syncthreads();
    for (int sft = 128; sft > 0; sft >>= 1) {
        if (tid < sft) red[tid] += red[tid + sft];
        __syncthreads();
    }
    float mean = red[0] * (1.0f / 1024.0f);
    __syncthreads();
    float c0 = v0 - mean, c1 = v1 - mean, c2 = v2 - mean, c3 = v3 - mean;
    red[tid] = c0 * c0 + c1 * c1 + c2 * c2 + c3 * c3;
    __syncthreads();
    for (int sft = 128; sft > 0; sft >>= 1) {
        if (tid < sft) red[tid] += red[tid + sft];
        __syncthreads();
    }
    float norm = sqrtf(red[0]);
    float* o = tn + bc * 1024;
    o[tid] = c0 / norm;
    o[tid + 256] = c1 / norm;
    o[tid + 512] = c2 / norm;
    o[tid + 768] = c3 / norm;
}

// ---------------------------------------------------------------------------
// Correlation: out[i,j] = sum_{u,v} Tn[u,v] * A[i-15+u, j-15+v] (A zero-pad).
// Block: 64 cols x 32 rows output; thread = 1 col x 8 consecutive rows.
// fp32 direct (VALU-bound). To be replaced by bf16 MFMA in later rounds.
// ---------------------------------------------------------------------------
__global__ __launch_bounds__(256) void k_corr(const float* __restrict__ A,
                                              const float* __restrict__ tn,
                                              float* __restrict__ out)
{
    __shared__ float s[63 * 96];            // rows i0-15..i0+47, cols j0-15..j0+79 (stride 96)
    __shared__ float sT[1024];
    const int j0 = blockIdx.x * 64;
    const int i0 = blockIdx.y * 32;
    const int bc = blockIdx.z;
    const int tid = threadIdx.x;
    const long plane = (long)bc * HH * WW;
    for (int k = tid; k < 63 * 96; k += 256) {
        int r = k / 96, c = k - r * 96;
        int gi = i0 + r - 15, gj = j0 + c - 15;
        float v = 0.f;
        if (c < 95 && gi >= 0 && gi < HH && gj >= 0 && gj < WW)
            v = A[plane + (long)gi * WW + gj];
        s[k] = v;
    }
    for (int k = tid; k < 1024; k += 256) sT[k] = tn[bc * 1024 + k];
    __syncthreads();

    const int tc = tid & 63;                // output column within tile (lane id)
    const int lr0 = (tid >> 6) * 8;         // first of 8 output rows
    float acc[8] = {0.f, 0.f, 0.f, 0.f, 0.f, 0.f, 0.f, 0.f};
    for (int v = 0; v < 32; v++) {
        float a[39];
#pragma unroll
        for (int m = 0; m < 39; m++) a[m] = s[(lr0 + m) * 96 + tc + v];
#pragma unroll
        for (int u = 0; u < 32; u++) {
            float tv = sT[u * 32 + v];      // broadcast, conflict-free
#pragma unroll
            for (int k = 0; k < 8; k++) acc[k] += tv * a[k + u];
        }
    }
#pragma unroll
    for (int k = 0; k < 8; k++) {
        int gi = i0 + lr0 + k;
        out[plane + (long)gi * WW + j0 + tc] = acc[k];
    }
}

// ---------------------------------------------------------------------------
// Orchestration. Buffers:
//   d_out : ping buffer for Hsum (P1) then H2 (P3); final output (k_corr)
//   d_ws  : [0, IMN) floats = im_c then A (in place);  [IMN, IMN+48*1024) = Tn
// Requires ws_size >= (IMN + 48*1024)*4 = 50,528,256 bytes.
// ---------------------------------------------------------------------------
extern "C" void kernel_launch(void* const* d_in, const int* in_sizes, int n_in,
                              void* d_out, int out_size, void* d_ws, size_t ws_size,
                              hipStream_t stream)
{
    const float* im = (const float*)d_in[0];
    const float* tmpl = (const float*)d_in[1];
    float* out = (float*)d_out;
    float* A = (float*)d_ws;
    float* Tn = A + IMN;

    // template normalization (independent)
    k_template<<<48, 256, 0, stream>>>(tmpl, Tn);
    // P1: horizontal box of im -> d_out (Hsum)
    k_hbox<<<BC * HH, 256, 0, stream>>>(im, out, 0);
    // P2: vertical box of Hsum + center: im_c -> ws
    k_vbox<<<dim3(8, 4, BC), 256, 0, stream>>>(out, im, A, 0);
    // P3: horizontal box of im_c^2 -> d_out (H2)
    k_hbox<<<BC * HH, 256, 0, stream>>>(A, out, 1);
    // P4: vertical box of H2 + normalize: A = im_c/energy -> ws (in place)
    k_vbox<<<dim3(8, 4, BC), 256, 0, stream>>>(out, A, A, 1);
    // correlation -> d_out
    k_corr<<<dim3(8, 16, BC), 256, 0, stream>>>(A, Tn, out);
}

// Round 2
// 447.206 us; speedup vs baseline: 1.3451x; 1.3451x over previous
//
#include <hip/hip_runtime.h>
#include <hip/hip_bf16.h>
#include <math.h>

#define HH 512
#define WW 512
#define BC 48
#define IMN (BC * HH * WW)        // 12,582,912
#define GW 544                    // padded width: 16 left + 512 + 16 right
#define GH 545                    // padded height: 16 top + 512 + 17 bottom
#define PST (GH * GW)             // plane stride in elements (296480)

typedef __bf16 v8bf __attribute__((ext_vector_type(8)));
typedef float v16f __attribute__((ext_vector_type(16)));

// ---------------------------------------------------------------------------
// P1: horizontal 32-tap box sum of im -> hs (fp32). One row per block.
// ---------------------------------------------------------------------------
__global__ __launch_bounds__(256) void k_hboxA(const float* __restrict__ src,
                                               float* __restrict__ dst)
{
    __shared__ float s[WW + 32];            // cols -15 .. 528
    const int row = blockIdx.x;             // bc*512 + i
    const long base = (long)row * WW;
    const int tid = threadIdx.x;
    for (int k = tid; k < WW + 32; k += 256) {
        int col = k - 15;
        s[k] = (col >= 0 && col < WW) ? src[base + col] : 0.f;
    }
    __syncthreads();
    for (int j = tid; j < WW; j += 256) {
        float sum = 0.f;
#pragma unroll
        for (int d = 0; d < 32; d++) sum += s[j + d];
        dst[base + j] = sum;
    }
}

// ---------------------------------------------------------------------------
// P3: horizontal 32-tap box sum of squared bf16 im_c (read from padded G0).
// Padding means no bounds checks. Output fp32 H2 -> hs.
// ---------------------------------------------------------------------------
__global__ __launch_bounds__(256) void k_hboxSq(const __hip_bfloat16* __restrict__ G0,
                                                float* __restrict__ dst)
{
    __shared__ float s[GW];
    const int row = blockIdx.x;             // bc*512 + i
    const int plane = row >> 9;
    const int i = row & 511;
    const __hip_bfloat16* rp = G0 + (size_t)plane * PST + (size_t)(16 + i) * GW;
    const int tid = threadIdx.x;
    for (int x = tid; x < GW; x += 256) {
        float v = __bfloat162float(rp[x]);
        s[x] = v * v;
    }
    __syncthreads();
    const long base = (long)row * WW;
    for (int j = tid; j < WW; j += 256) {
        float sum = 0.f;
#pragma unroll
        for (int d = 0; d < 32; d++) sum += s[j + 1 + d];   // idx j+1..j+32 = cols j-15..j+16
        dst[base + j] = sum;
    }
}

// ---------------------------------------------------------------------------
// P2: vertical 32-tap box of hs, center im, write bf16 im_c into padded dual
// copies G0/G1 (G1 shifted left one column). Edge blocks also zero the pads.
// ---------------------------------------------------------------------------
__global__ __launch_bounds__(256) void k_center(const float* __restrict__ hs,
                                                const float* __restrict__ im,
                                                __hip_bfloat16* __restrict__ G0,
                                                __hip_bfloat16* __restrict__ G1)
{
    __shared__ float s[159 * 64];
    const int j0 = blockIdx.x * 64;
    const int i0 = blockIdx.y * 128;
    const int plane = blockIdx.z;
    const int tid = threadIdx.x;
    const size_t iplane = (size_t)plane * HH * WW;
    const size_t gplane = (size_t)plane * PST;
    for (int k = tid; k < 159 * 64; k += 256) {
        int r = k >> 6, c = k & 63;
        int gi = i0 + r - 15;
        s[k] = (gi >= 0 && gi < HH) ? hs[iplane + (size_t)gi * WW + j0 + c] : 0.f;
    }
    __syncthreads();
    const int tc = tid & 63;
    const int lr0 = (tid >> 6) * 32;
    float run = 0.f;
#pragma unroll
    for (int d = 0; d < 32; d++) run += s[(lr0 + d) * 64 + tc];
    for (int rr = 0; rr < 32; rr++) {
        int lr = lr0 + rr;
        int gi = i0 + lr;
        int c = j0 + tc;
        float val = im[iplane + (size_t)gi * WW + c] - run * (1.0f / 1024.0f);
        __hip_bfloat16 w = __float2bfloat16(val);
        size_t pr = gplane + (size_t)(16 + gi) * GW;
        G0[pr + 16 + c] = w;
        G1[pr + 15 + c] = w;
        if (rr < 31) run += s[(lr + 32) * 64 + tc] - s[lr * 64 + tc];
    }
    // ---- pad zeroing (disjoint addresses from all data writes) ----
    if (blockIdx.x == 0) {
        // left col pads for this block's 128 rows: G0 [0,16), G1 [0,15)
        for (int k = tid; k < 128 * 16; k += 256) {
            int rr = k >> 4, x = k & 15;
            size_t pr = gplane + (size_t)(16 + i0 + rr) * GW;
            G0[pr + x] = __float2bfloat16(0.f);
            if (x < 15) G1[pr + x] = __float2bfloat16(0.f);
        }
    }
    if (blockIdx.x == 7) {
        // right col pads: G0 [528,544), G1 [527,544)
        for (int k = tid; k < 128 * 17; k += 256) {
            int rr = k / 17, x = k % 17;
            size_t pr = gplane + (size_t)(16 + i0 + rr) * GW;
            G1[pr + 527 + x] = __float2bfloat16(0.f);
            if (x > 0) G0[pr + 527 + x] = __float2bfloat16(0.f);
        }
    }
    if (blockIdx.x == 0 && blockIdx.y == 0) {
        // top pad rows [0,16): first 16*GW elements of the plane
        for (int k = tid; k < 16 * GW; k += 256) {
            G0[gplane + k] = __float2bfloat16(0.f);
            G1[gplane + k] = __float2bfloat16(0.f);
        }
    }
    if (blockIdx.x == 0 && blockIdx.y == 3) {
        // bottom pad rows [528,545): 17 rows
        size_t b = gplane + (size_t)528 * GW;
        for (int k = tid; k < 17 * GW; k += 256) {
            G0[b + k] = __float2bfloat16(0.f);
            G1[b + k] = __float2bfloat16(0.f);
        }
    }
}

// ---------------------------------------------------------------------------
// P4: vertical 32-tap box of H2 -> energy; normalize G0/G1 in place.
// ---------------------------------------------------------------------------
__global__ __launch_bounds__(256) void k_normalize(const float* __restrict__ hs,
                                                   __hip_bfloat16* __restrict__ G0,
                                                   __hip_bfloat16* __restrict__ G1)
{
    __shared__ float s[159 * 64];
    const int j0 = blockIdx.x * 64;
    const int i0 = blockIdx.y * 128;
    const int plane = blockIdx.z;
    const int tid = threadIdx.x;
    const size_t iplane = (size_t)plane * HH * WW;
    const size_t gplane = (size_t)plane * PST;
    for (int k = tid; k < 159 * 64; k += 256) {
        int r = k >> 6, c = k & 63;
        int gi = i0 + r - 15;
        s[k] = (gi >= 0 && gi < HH) ? hs[iplane + (size_t)gi * WW + j0 + c] : 0.f;
    }
    __syncthreads();
    const int tc = tid & 63;
    const int lr0 = (tid >> 6) * 32;
    float run = 0.f;
#pragma unroll
    for (int d = 0; d < 32; d++) run += s[(lr0 + d) * 64 + tc];
    for (int rr = 0; rr < 32; rr++) {
        int lr = lr0 + rr;
        int gi = i0 + lr;
        int c = j0 + tc;
        float e = sqrtf(fmaxf(run, 0.f));
        size_t pr = gplane + (size_t)(16 + gi) * GW;
        float v = __bfloat162float(G0[pr + 16 + c]) / e;
        __hip_bfloat16 w = __float2bfloat16(v);
        G0[pr + 16 + c] = w;
        G1[pr + 15 + c] = w;
        if (rr < 31) run += s[(lr + 32) * 64 + tc] - s[lr * 64 + tc];
    }
}

// ---------------------------------------------------------------------------
// Template normalization: Tn = (t - mean)/||t - mean|| per (b,c), bf16 out.
// ---------------------------------------------------------------------------
__global__ __launch_bounds__(256) void k_template(const float* __restrict__ t,
                                                  __hip_bfloat16* __restrict__ tn)
{
    __shared__ float red[256];
    const int bc = blockIdx.x, tid = threadIdx.x;
    const float* tp = t + bc * 1024;
    float v0 = tp[tid], v1 = tp[tid + 256], v2 = tp[tid + 512], v3 = tp[tid + 768];
    red[tid] = v0 + v1 + v2 + v3;
    __syncthreads();
    for (int sft = 128; sft > 0; sft >>= 1) {
        if (tid < sft) red[tid] += red[tid + sft];
        __syncthreads();
    }
    float mean = red[0] * (1.0f / 1024.0f);
    __syncthreads();
    float c0 = v0 - mean, c1 = v1 - mean, c2 = v2 - mean, c3 = v3 - mean;
    red[tid] = c0 * c0 + c1 * c1 + c2 * c2 + c3 * c3;
    __syncthreads();
    for (int sft = 128; sft > 0; sft >>= 1) {
        if (tid < sft) red[tid] += red[tid + sft];
        __syncthreads();
    }
    float norm = sqrtf(red[0]);
    __hip_bfloat16* o = tn + bc * 1024;
    o[tid] = __float2bfloat16(c0 / norm);
    o[tid + 256] = __float2bfloat16(c1 / norm);
    o[tid + 512] = __float2bfloat16(c2 / norm);
    o[tid + 768] = __float2bfloat16(c3 / norm);
}

// ---------------------------------------------------------------------------
// Correlation via MFMA scatter scheme.
// Per wave: 32 output cols, 128 output rows, sweep 160 image rows.
// P[u][col] = sum_v Tn[u,v] * A[r, col+v-15]; contributes to out[r+15-u][col].
// A-operand (Tn) lives in registers; B read straight from global dual-copy.
// Rotating 32-slot ring, statically indexed via 32-unrolled t loop.
// C/D layout (measured m74/m101): col=lane&31, row=(reg&3)+8*(reg>>2)+4*(lane>>5).
// ---------------------------------------------------------------------------
__global__ __launch_bounds__(256) void k_corr_mfma(const __hip_bfloat16* __restrict__ G0,
                                                   const __hip_bfloat16* __restrict__ G1,
                                                   const __hip_bfloat16* __restrict__ Tn,
                                                   float* __restrict__ out)
{
    const int tid = threadIdx.x;
    const int wid = tid >> 6;
    const int lane = tid & 63;
    const int n = lane & 31;            // MFMA col (output column within wave tile)
    const int h = lane >> 5;            // lane half
    const int j0w = blockIdx.x * 128 + wid * 32;
    const int i0 = blockIdx.y * 128;    // multiple of 32 (required for static ring idx)
    const int plane = blockIdx.z;

    // A-operand: Tn fragments, loaded once. A[m=u=lane&31][k=v=8h+j (+16)]
    const v8bf* tp = (const v8bf*)(Tn + (size_t)plane * 1024 + n * 32 + 8 * h);
    const v8bf a0 = tp[0];
    const v8bf a1 = tp[2];

    // B pointer: lane's 8 image cols start at c0 = j0w + n - 15 + 8h (+16 for khalf1).
    // Parity-select between G0 and col-shifted G1 so the 16B load is 4B-aligned.
    const int c0 = j0w + n - 15 + 8 * h;
    const int sel = c0 & 1;
    const __hip_bfloat16* gsel = sel ? G1 : G0;
    // phys row for image row r is 16+r; sweep starts at r = i0-15 -> phys i0+1
    const __hip_bfloat16* pb = gsel + (size_t)plane * PST
                             + (size_t)(i0 + 1) * GW + 16 + (c0 - sel);

    float ring[32];
#pragma unroll
    for (int s = 0; s < 32; s++) ring[s] = 0.f;
    const v16f Z = 0.0f;

    for (int blk = 0; blk < 5; ++blk) {
#pragma unroll
        for (int t = 0; t < 32; ++t) {
            const v8bf* rp = (const v8bf*)(pb + (size_t)(32 * blk + t) * GW);
            v8bf b0 = rp[0];
            v8bf b1 = rp[2];
            v16f P = __builtin_amdgcn_mfma_f32_32x32x16_bf16(a0, b0, Z, 0, 0, 0);
            P = __builtin_amdgcn_mfma_f32_32x32x16_bf16(a1, b1, P, 0, 0, 0);
            // scatter into rotating ring (phys slot = logical + 4h; add idx static)
#pragma unroll
            for (int q = 0; q < 16; ++q) {
                const int baseq = (q & 3) + 8 * (q >> 2);
                ring[(t - baseq) & 31] += P[q];
            }
            // retire row ret = r-16; its phys slot is (t+1) for h=0, (t+5) for h=1
            float va = ring[(t + 1) & 31];
            float vb = ring[(t + 5) & 31];
            float val = h ? vb : va;
            val += __shfl_xor(val, 32);
            const int ret = i0 - 31 + 32 * blk + t;
            if (ret >= i0 && ret < i0 + 128 && ret < HH) {
                if (h == 0)
                    out[(size_t)plane * HH * WW + (size_t)ret * WW + j0w + n] = val;
            }
            ring[(t + 1) & 31] = h ? va : 0.f;
            ring[(t + 5) & 31] = h ? 0.f : vb;
        }
    }
}

// ---------------------------------------------------------------------------
// Orchestration.
//   d_out : Hsum (P1) -> H2 (P3) -> final output (corr)
//   d_ws  : G0 (bf16 padded), G1 (bf16 padded, col-shifted), Tn (bf16)
// ws needed: 2*48*545*544*2 + 48*1024*2 = 57.0 MB
// ---------------------------------------------------------------------------
extern "C" void kernel_launch(void* const* d_in, const int* in_sizes, int n_in,
                              void* d_out, int out_size, void* d_ws, size_t ws_size,
                              hipStream_t stream)
{
    const float* im = (const float*)d_in[0];
    const float* tmpl = (const float*)d_in[1];
    float* hs = (float*)d_out;
    __hip_bfloat16* G0 = (__hip_bfloat16*)d_ws;
    __hip_bfloat16* G1 = G0 + (size_t)BC * PST;
    __hip_bfloat16* Tn = G1 + (size_t)BC * PST;

    k_template<<<48, 256, 0, stream>>>(tmpl, Tn);
    k_hboxA<<<BC * HH, 256, 0, stream>>>(im, hs);
    k_center<<<dim3(8, 4, BC), 256, 0, stream>>>(hs, im, G0, G1);
    k_hboxSq<<<BC * HH, 256, 0, stream>>>(G0, hs);
    k_normalize<<<dim3(8, 4, BC), 256, 0, stream>>>(hs, G0, G1);
    k_corr_mfma<<<dim3(4, 4, BC), 256, 0, stream>>>(G0, G1, Tn, hs);
}